// Round 7
// baseline (249.014 us; speedup 1.0000x reference)
//
#include <hip/hip_runtime.h>

#define EPS 1e-5f
#define B 16
#define CH 22
#define CH2 24            // padded channel count (rows 22,23 zero)
#define T_IN 1001
#define F 36
#define RF 65
#define T1 937            // T_IN - RF + 1
#define FC 792            // F*CH
#define UN 885            // valid u range for Q/E
#define PS3 112           // qconv staged span per f row (need 106, pad to 112)
#define KS 15
#define GN 295
#define WN 129
#define M43 43
#define BF 576            // B*F
#define FLAT 1548         // F*43

// workspace float offsets
#define H2_OFF  0                 // 576*937       =   539,712
#define A_OFF   539712            // A[bf][u]: 576*885 = 509,760
#define WTG_OFF 4617792           // + 4*33*24     =     3,168  (wtG[g][kp][24])
#define WST_OFF 4620960           // + 36*24*36    =    31,104  (wsTp, ch-padded)
#define WCT_OFF 4652064           // + 36*15*36    =    19,440
#define BN_OFF  4671504           // + 6*36        =       216

__device__ __forceinline__ float elu_f(float v) {
    return v > 0.f ? v : (__expf(v) - 1.f);
}

// ---- prep: pack weights + bn scale/offset + init out with bias -------------
__global__ __launch_bounds__(256) void k_prep(
    const float* __restrict__ w_t, const float* __restrict__ w_s,
    const float* __restrict__ w_c,
    const float* __restrict__ b_t, const float* __restrict__ g_t,
    const float* __restrict__ be_t,const float* __restrict__ m_t,
    const float* __restrict__ v_t,
    const float* __restrict__ b_s, const float* __restrict__ g_s,
    const float* __restrict__ be_s,const float* __restrict__ m_s,
    const float* __restrict__ v_s,
    const float* __restrict__ b_c, const float* __restrict__ g_c,
    const float* __restrict__ be_c,const float* __restrict__ m_c,
    const float* __restrict__ v_c, const float* __restrict__ b_fc,
    float* __restrict__ wtG, float* __restrict__ wsTp,
    float* __restrict__ wcT, float* __restrict__ bnz,
    float* __restrict__ out)
{
    int i = blockIdx.x * 256 + threadIdx.x;
    if (i < 4 * 33 * 24) {            // wtG[g][kp][kk*12+j] = w_t[g*9+j][2kp+kk]
        int g  = i / (33 * 24);
        int r  = i % (33 * 24);
        int kp = r / 24, slot = r % 24;
        int kk = slot / 12, j = slot % 12;
        int k  = 2 * kp + kk;
        wtG[i] = (j < 9 && k < RF) ? w_t[(g * 9 + j) * RF + k] : 0.f;
    }
    if (i < F * CH2 * F) {            // wsTp[(fi*24+ch)*F+fo], pad ch>=22 with 0
        int fi = i / (CH2 * F);
        int r  = i % (CH2 * F);
        int ch = r / F, fo = r % F;
        wsTp[i] = (ch < CH) ? w_s[(fo * F + fi) * CH + ch] : 0.f;
    }
    if (i < F * KS * F) { int fk = i / F, fo = i % F; int f = fk / KS, k = fk % KS;
                          wcT[i] = w_c[(fo * F + f) * KS + k]; }
    if (i < F) {
        float s1 = g_t[i] * rsqrtf(v_t[i] + EPS);
        bnz[i]          = s1;
        bnz[F + i]      = (b_t[i] - m_t[i]) * s1 + be_t[i];
        float s2 = g_s[i] * rsqrtf(v_s[i] + EPS);
        bnz[2 * F + i]  = s2;
        bnz[3 * F + i]  = (b_s[i] - m_s[i]) * s2 + be_s[i];
        float s3 = g_c[i] * rsqrtf(v_c[i] + EPS);
        bnz[4 * F + i]  = s3;
        bnz[5 * F + i]  = (b_c[i] - m_c[i]) * s3 + be_c[i];
    }
    if (i < B * 4) out[i] = b_fc[i & 3];
}

// ---- K1: FUSED tconv + bn_t + elu + sconv + bn_s + elu  --------------------
// v7 pipe separation (v6 was stalled on lgkmcnt(0) waits that mixed
// out-of-order SMEM weight loads with in-order ds_read x loads — VALUBusy 30%):
//   * x -> VMEM: 17 overlapping float4 global loads per channel into regs
//     (coalesced, L1/L3-resident, vmcnt-batched). NO LDS staging, no barrier.
//   * weights -> SMEM only: wtG[g][kp][24] packs the wave's 9fi x 2k into one
//     contiguous 96B run -> s_load_dwordx16+x8 per k-pair, batchable in SGPRs.
//   * LDS used ONLY by the combine tree.
// grid (15, B) = 240 blocks x 1024 thr = 16 waves (4/SIMD, 1 block/CU).
// VGPR: acc[36]+h1a[9]+xv[33]+addr ~ 90 < 128 @ (1024,4): no spill.
__global__ __launch_bounds__(1024, 4) void k_fused(
    const float* __restrict__ x, const float* __restrict__ wtG,
    const float* __restrict__ wsTp, const float* __restrict__ bnz,
    float* __restrict__ h2)
{
    __shared__ float comb[8][64][F];      // 73.7 KB
    const int tid  = threadIdx.x;
    const int lane = tid & 63;
    const int w = __builtin_amdgcn_readfirstlane(tid >> 6);  // 0..15 (uniform)
    const int q = w >> 2;       // ch sextet of CH2=24
    const int g = w & 3;        // fi group (9)
    const int b  = blockIdx.y;
    const int t0 = blockIdx.x * 64;

    int t  = t0 + lane;
    int tcl = t < (T1 - 1) ? t : (T1 - 1);   // clamp: max read idx 936+64=1000

    const int ch0 = q * 6;
    const int fi0 = g * 9;
    const float* wgB = wtG + g * (33 * 24);

    float acc[F];
    #pragma unroll
    for (int fo = 0; fo < F; ++fo) acc[fo] = 0.f;

    for (int c = 0; c < 6; ++c) {
        const int ch = ch0 + c;
        if (ch < CH) {                       // wave-uniform branch (q,c uniform)
            const float* xp = x + (b * CH + ch) * T_IN + tcl;

            float h1a[9];
            #pragma unroll
            for (int j = 0; j < 9; ++j) h1a[j] = 0.f;

            {   // phase A: k in [0,32) — pure VMEM then pure SMEM+FMA
                float xv[32];
                #pragma unroll
                for (int m = 0; m < 8; ++m) {
                    float4 v = *(const float4*)(xp + 4 * m);
                    xv[4*m] = v.x; xv[4*m+1] = v.y; xv[4*m+2] = v.z; xv[4*m+3] = v.w;
                }
                #pragma unroll
                for (int kp = 0; kp < 16; ++kp) {
                    const float* wp = wgB + kp * 24;   // 24 consec floats, uniform
                    float x0 = xv[2*kp], x1 = xv[2*kp+1];
                    #pragma unroll
                    for (int j = 0; j < 9; ++j)
                        h1a[j] += x0 * wp[j] + x1 * wp[12 + j];
                }
            }
            {   // phase B: k in [32,64]
                float xv[33];
                #pragma unroll
                for (int m = 0; m < 8; ++m) {
                    float4 v = *(const float4*)(xp + 32 + 4 * m);
                    xv[4*m] = v.x; xv[4*m+1] = v.y; xv[4*m+2] = v.z; xv[4*m+3] = v.w;
                }
                xv[32] = xp[64];
                #pragma unroll
                for (int kp = 0; kp < 16; ++kp) {
                    const float* wp = wgB + (16 + kp) * 24;
                    float x0 = xv[2*kp], x1 = xv[2*kp+1];
                    #pragma unroll
                    for (int j = 0; j < 9; ++j)
                        h1a[j] += x0 * wp[j] + x1 * wp[12 + j];
                }
                const float* wp = wgB + 32 * 24;       // tail k = 64
                #pragma unroll
                for (int j = 0; j < 9; ++j) h1a[j] += xv[32] * wp[j];
            }

            // bn_t + elu in-register (bnz wave-uniform -> SGPR)
            #pragma unroll
            for (int j = 0; j < 9; ++j)
                h1a[j] = elu_f(h1a[j] * bnz[fi0 + j] + bnz[F + fi0 + j]);

            // sconv fold: acc[fo] += h1a[j] * wsTp[(fi0+j)*24 + ch][fo]
            #pragma unroll
            for (int j = 0; j < 9; ++j) {
                const float* wr = wsTp + ((fi0 + j) * CH2 + ch) * F;  // 36 consec
                float e = h1a[j];
                #pragma unroll
                for (int fo = 0; fo < F; ++fo)
                    acc[fo] += e * wr[fo];
            }
        }
    }

    // combine 16 K-partials -> wave 0 (4 rounds, float4 LDS)
    for (int half = 8; half >= 1; half >>= 1) {
        if (w >= half && w < 2 * half) {
            float4* cb = (float4*)&comb[w - half][lane][0];
            #pragma unroll
            for (int j = 0; j < 9; ++j)
                cb[j] = make_float4(acc[4*j], acc[4*j+1], acc[4*j+2], acc[4*j+3]);
        }
        __syncthreads();
        if (w < half) {
            const float4* cb = (const float4*)&comb[w][lane][0];
            #pragma unroll
            for (int j = 0; j < 9; ++j) {
                float4 v = cb[j];
                acc[4*j]   += v.x; acc[4*j+1] += v.y;
                acc[4*j+2] += v.z; acc[4*j+3] += v.w;
            }
        }
        __syncthreads();
    }

    if (w == 0) {
        if (t < T1) {
            #pragma unroll
            for (int fo = 0; fo < F; ++fo) {
                float s2 = bnz[2 * F + fo], o2 = bnz[3 * F + fo];
                h2[(b * F + fo) * T1 + t] = elu_f(acc[fo] * s2 + o2);
            }
        }
    }
}

// ---- K2: fused pool3 + dilated conv + bn_c + elu -> A[bf][u] ---------------
// 12 waves, wave = 3-f K-slice with PRIVATE Ps staging (no barriers in main
// loop), acc[36] in registers, combine tree. (768, 3): 3 waves/SIMD cap.
__global__ __launch_bounds__(768, 3) void k_qconv(
    const float* __restrict__ h2, const float* __restrict__ wcT,
    const float* __restrict__ bnz, float* __restrict__ A)
{
    __shared__ float Ps[12][3][PS3];      // 16.1 KB
    __shared__ float comb[6][64][F];      // 55.3 KB
    const int tid  = threadIdx.x;
    const int lane = tid & 63;
    const int w = __builtin_amdgcn_readfirstlane(tid >> 6);  // 0..11
    const int b  = blockIdx.y;
    const int u0 = blockIdx.x * 64;
    const int f0 = w * 3;

    // per-wave private pooled staging (same-wave dep -> compiler lgkmcnt)
    for (int i = lane; i < 3 * PS3; i += 64) {
        int fl = i / PS3, j = i % PS3;
        const float* hr = h2 + (size_t)(b * F + f0 + fl) * T1;
        int s = u0 + j;
        int s0 = s     < T1 - 1 ? s     : T1 - 1;
        int s1 = s + 1 < T1 - 1 ? s + 1 : T1 - 1;
        int s2 = s + 2 < T1 - 1 ? s + 2 : T1 - 1;
        Ps[w][fl][j] = (hr[s0] + hr[s1] + hr[s2]) * (1.f / 3.f);
    }

    float acc[F];
    #pragma unroll
    for (int j = 0; j < F; ++j) acc[j] = 0.f;

    #pragma unroll
    for (int fl = 0; fl < 3; ++fl) {
        #pragma unroll
        for (int k = 0; k < KS; ++k) {
            float pv = Ps[w][fl][lane + 3 * k];
            const float* wr = wcT + ((f0 + fl) * KS + k) * F;  // 36 consec
            #pragma unroll
            for (int fo = 0; fo < F; ++fo) acc[fo] += pv * wr[fo];
        }
    }

    // combine 12 -> 1: rounds 6, 3, then 2-buffer finish
    if (w >= 6) {
        float4* cb = (float4*)&comb[w - 6][lane][0];
        #pragma unroll
        for (int j = 0; j < 9; ++j)
            cb[j] = make_float4(acc[4*j], acc[4*j+1], acc[4*j+2], acc[4*j+3]);
    }
    __syncthreads();
    if (w < 6) {
        const float4* cb = (const float4*)&comb[w][lane][0];
        #pragma unroll
        for (int j = 0; j < 9; ++j) {
            float4 v = cb[j];
            acc[4*j] += v.x; acc[4*j+1] += v.y; acc[4*j+2] += v.z; acc[4*j+3] += v.w;
        }
    }
    __syncthreads();
    if (w >= 3 && w < 6) {
        float4* cb = (float4*)&comb[w - 3][lane][0];
        #pragma unroll
        for (int j = 0; j < 9; ++j)
            cb[j] = make_float4(acc[4*j], acc[4*j+1], acc[4*j+2], acc[4*j+3]);
    }
    __syncthreads();
    if (w < 3) {
        const float4* cb = (const float4*)&comb[w][lane][0];
        #pragma unroll
        for (int j = 0; j < 9; ++j) {
            float4 v = cb[j];
            acc[4*j] += v.x; acc[4*j+1] += v.y; acc[4*j+2] += v.z; acc[4*j+3] += v.w;
        }
    }
    __syncthreads();
    if (w == 1 || w == 2) {
        float4* cb = (float4*)&comb[w - 1][lane][0];
        #pragma unroll
        for (int j = 0; j < 9; ++j)
            cb[j] = make_float4(acc[4*j], acc[4*j+1], acc[4*j+2], acc[4*j+3]);
    }
    __syncthreads();
    if (w == 0) {
        #pragma unroll
        for (int j = 0; j < 9; ++j) {
            float4 v0 = ((const float4*)&comb[0][lane][0])[j];
            float4 v1 = ((const float4*)&comb[1][lane][0])[j];
            acc[4*j]   += v0.x + v1.x; acc[4*j+1] += v0.y + v1.y;
            acc[4*j+2] += v0.z + v1.z; acc[4*j+3] += v0.w + v1.w;
        }
        int u_g = u0 + lane;
        if (u_g < UN) {
            #pragma unroll
            for (int fo = 0; fo < F; ++fo) {
                float sc = bnz[4 * F + fo], oc = bnz[5 * F + fo];
                A[((size_t)(b * F + fo)) * UN + u_g] = elu_f(acc[fo] * sc + oc);
            }
        }
    }
}

// ---- K3: window sums over finished A + fused FC -> atomicAdd out -----------
__global__ __launch_bounds__(256) void k_wins(
    const float* __restrict__ A, const float* __restrict__ w_fc,
    float* __restrict__ out)
{
    __shared__ float Es[UN];
    __shared__ float G[GN];
    __shared__ float Ws[WN];
    __shared__ float Sm[M43];
    const int tid = threadIdx.x;
    const int bf = blockIdx.x;
    const int b = bf / F, f = bf % F;
    for (int i = tid; i < UN; i += 256)
        Es[i] = A[(size_t)bf * UN + i];
    __syncthreads();
    for (int q = tid; q < GN; q += 256)
        G[q] = Es[3 * q] + Es[3 * q + 1] + Es[3 * q + 2];
    __syncthreads();
    if (tid < WN) {
        float a = 0.f;
        for (int q = tid; q < tid + 167; ++q) a += G[q];
        Ws[tid] = a;
    }
    __syncthreads();
    if (tid < M43)
        Sm[tid] = (Ws[3 * tid] + Ws[3 * tid + 1] + Ws[3 * tid + 2]) * (1.f / 3.f);
    __syncthreads();
    if (tid < 4) {
        const float* wr = w_fc + tid * FLAT + f * M43;
        float a = 0.f;
        #pragma unroll 43
        for (int m = 0; m < M43; ++m) a += Sm[m] * wr[m];
        atomicAdd(&out[b * 4 + tid], a * (1.f / 501.f));
    }
}

extern "C" void kernel_launch(void* const* d_in, const int* in_sizes, int n_in,
                              void* d_out, int out_size, void* d_ws, size_t ws_size,
                              hipStream_t stream) {
    const float* x    = (const float*)d_in[0];
    const float* w_t  = (const float*)d_in[1];
    const float* b_t  = (const float*)d_in[2];
    const float* g_t  = (const float*)d_in[3];
    const float* be_t = (const float*)d_in[4];
    const float* m_t  = (const float*)d_in[5];
    const float* v_t  = (const float*)d_in[6];
    const float* w_s  = (const float*)d_in[7];
    const float* b_s  = (const float*)d_in[8];
    const float* g_s  = (const float*)d_in[9];
    const float* be_s = (const float*)d_in[10];
    const float* m_s  = (const float*)d_in[11];
    const float* v_s  = (const float*)d_in[12];
    const float* w_c  = (const float*)d_in[13];
    const float* b_c  = (const float*)d_in[14];
    const float* g_c  = (const float*)d_in[15];
    const float* be_c = (const float*)d_in[16];
    const float* m_c  = (const float*)d_in[17];
    const float* v_c  = (const float*)d_in[18];
    const float* w_fc = (const float*)d_in[19];
    const float* b_fc = (const float*)d_in[20];

    float* ws   = (float*)d_ws;
    float* h2   = ws + H2_OFF;
    float* A    = ws + A_OFF;
    float* wtG  = ws + WTG_OFF;
    float* wsTp = ws + WST_OFF;
    float* wcT  = ws + WCT_OFF;
    float* bnz  = ws + BN_OFF;
    float* out  = (float*)d_out;

    k_prep<<<dim3(128), 256, 0, stream>>>(
        w_t, w_s, w_c, b_t, g_t, be_t, m_t, v_t,
        b_s, g_s, be_s, m_s, v_s, b_c, g_c, be_c, m_c, v_c, b_fc,
        wtG, wsTp, wcT, bnz, out);

    k_fused<<<dim3(15, B), 1024, 0, stream>>>(x, wtG, wsTp, bnz, h2);
    k_qconv<<<dim3(14, B), 768, 0, stream>>>(h2, wcT, bnz, A);
    k_wins<<<dim3(BF), 256, 0, stream>>>(A, w_fc, out);
}

// Round 8
// 200.330 us; speedup vs baseline: 1.2430x; 1.2430x over previous
//
#include <hip/hip_runtime.h>

#define EPS 1e-5f
#define B 16
#define CH 22
#define CH2 24            // padded channel count (rows 22,23 zero)
#define T_IN 1001
#define F 36
#define RF 65
#define T1 937            // T_IN - RF + 1
#define FC 792            // F*CH
#define UN 885            // valid u range for Q/E
#define PSP 944           // padded pooled-row length (need 938)
#define KS 15
#define GN 295
#define WN 129
#define M43 43
#define BF 576            // B*F
#define FLAT 1548         // F*43

// workspace float offsets
#define H2_OFF  0                 // 576*937        =   539,712
#define A_OFF   539712            // A[bf][u]: 576*885 = 509,760 -> ends 1,049,472
#define P_OFF   1049472           // P[bf][944]: 576*944 = 543,744 -> ends 1,593,216
#define WTT_OFF 4617792           // + 65*36        =     2,340  (wtT[k][fi])
#define WST_OFF 4620132           // + 36*24*36     =    31,104  (wsTp, ch-padded)
#define WCQ_OFF 4651236           // + 12*36*15*4   =    25,920  (wcQ[t3][f][k][4])
#define BN_OFF  4677156           // + 6*36         =       216

__device__ __forceinline__ float elu_f(float v) {
    return v > 0.f ? v : (__expf(v) - 1.f);
}

// ---- prep: transpose/pack weights + bn scale/offset + init out with bias ---
__global__ __launch_bounds__(256) void k_prep(
    const float* __restrict__ w_t, const float* __restrict__ w_s,
    const float* __restrict__ w_c,
    const float* __restrict__ b_t, const float* __restrict__ g_t,
    const float* __restrict__ be_t,const float* __restrict__ m_t,
    const float* __restrict__ v_t,
    const float* __restrict__ b_s, const float* __restrict__ g_s,
    const float* __restrict__ be_s,const float* __restrict__ m_s,
    const float* __restrict__ v_s,
    const float* __restrict__ b_c, const float* __restrict__ g_c,
    const float* __restrict__ be_c,const float* __restrict__ m_c,
    const float* __restrict__ v_c, const float* __restrict__ b_fc,
    float* __restrict__ wtT, float* __restrict__ wsTp,
    float* __restrict__ wcQ, float* __restrict__ bnz,
    float* __restrict__ out)
{
    int i = blockIdx.x * 256 + threadIdx.x;
    if (i < F * RF)     { int k = i / F,  fi = i % F; wtT[i] = w_t[fi * RF + k]; }
    if (i < F * CH2 * F) {            // wsTp[(fi*24+ch)*F+fo], pad ch>=22 with 0
        int fi = i / (CH2 * F);
        int r  = i % (CH2 * F);
        int ch = r / F, fo = r % F;
        wsTp[i] = (ch < CH) ? w_s[(fo * F + fi) * CH + ch] : 0.f;
    }
    if (i < 12 * 36 * 15 * 4) {       // wcQ[t3][f][k][j] = w_c[3*t3+j][f][k]
        int t3 = i / (36 * 15 * 4);
        int r  = i % (36 * 15 * 4);
        int f  = r / 60;
        int r2 = r % 60;
        int k  = r2 / 4, j = r2 % 4;
        wcQ[i] = (j < 3) ? w_c[((3 * t3 + j) * F + f) * KS + k] : 0.f;
    }
    if (i < F) {
        float s1 = g_t[i] * rsqrtf(v_t[i] + EPS);
        bnz[i]          = s1;
        bnz[F + i]      = (b_t[i] - m_t[i]) * s1 + be_t[i];
        float s2 = g_s[i] * rsqrtf(v_s[i] + EPS);
        bnz[2 * F + i]  = s2;
        bnz[3 * F + i]  = (b_s[i] - m_s[i]) * s2 + be_s[i];
        float s3 = g_c[i] * rsqrtf(v_c[i] + EPS);
        bnz[4 * F + i]  = s3;
        bnz[5 * F + i]  = (b_c[i] - m_c[i]) * s3 + be_c[i];
    }
    if (i < B * 4) out[i] = b_fc[i & 3];
}

// ---- K1: FUSED tconv + bn_t + elu + sconv + bn_s + elu  --------------------
// EXACT round-6 version (measured 69.4 us, 52 VGPR, no spill). Lesson from
// rounds 5/7: this compiler caps 1024-thread kernels at 64 VGPRs regardless
// of __launch_bounds__; any design must stay under ~60 live floats.
__global__ __launch_bounds__(1024, 4) void k_fused(
    const float* __restrict__ x, const float* __restrict__ wtT,
    const float* __restrict__ wsTp, const float* __restrict__ bnz,
    float* __restrict__ h2)
{
    __shared__ float xs[CH2 * 128];       // 12.3 KB
    __shared__ float comb[8][64][F];      // 73.7 KB  -> total 86 KB
    const int tid  = threadIdx.x;
    const int lane = tid & 63;
    const int w = __builtin_amdgcn_readfirstlane(tid >> 6);  // 0..15 (uniform)
    const int q = w >> 2;       // ch sextet of CH2=24
    const int g = w & 3;        // fi group
    const int b  = blockIdx.y;
    const int t0 = blockIdx.x * 64;

    // stage x window [24 ch][128 t] (pad ch>=22 with 0; clamp t)
    for (int i = tid; i < CH2 * 128; i += 1024) {
        int ch = i >> 7, j = i & 127;
        int t = t0 + j; if (t > T_IN - 1) t = T_IN - 1;
        xs[i] = (ch < CH) ? x[(b * CH + ch) * T_IN + t] : 0.f;
    }
    __syncthreads();

    const int ch0 = q * 6;
    const int fi0 = g * 9;

    float acc[F];
    #pragma unroll
    for (int fo = 0; fo < F; ++fo) acc[fo] = 0.f;

    for (int c = 0; c < 6; ++c) {
        const float* xr = xs + (ch0 + c) * 128 + lane;

        float h1a[9];
        #pragma unroll
        for (int j = 0; j < 9; ++j) h1a[j] = 0.f;

        #pragma unroll 8
        for (int kp = 0; kp < 32; ++kp) {
            const int k = 2 * kp;
            float xv0 = xr[k];                    // adjacent dword offsets ->
            float xv1 = xr[k + 1];                //   ds_read2_b32 merge
            const float* w0 = wtT + k * F + fi0;  // wave-uniform -> s_load
            const float* w1 = w0 + F;
            #pragma unroll
            for (int j = 0; j < 9; ++j) {
                h1a[j] += xv0 * w0[j];
                h1a[j] += xv1 * w1[j];
            }
        }
        {   // tail k = 64
            float xv = xr[64];
            const float* w64 = wtT + 64 * F + fi0;
            #pragma unroll
            for (int j = 0; j < 9; ++j) h1a[j] += xv * w64[j];
        }

        // bn_t + elu in-register (bnz reads wave-uniform -> SGPR)
        #pragma unroll
        for (int j = 0; j < 9; ++j)
            h1a[j] = elu_f(h1a[j] * bnz[fi0 + j] + bnz[F + fi0 + j]);

        // sconv fold: acc[fo] += h1a[j] * wsTp[(fi0+j)*24 + ch0+c][fo]
        #pragma unroll
        for (int j = 0; j < 9; ++j) {
            const float* wr = wsTp + ((fi0 + j) * CH2 + ch0 + c) * F;
            float e = h1a[j];
            #pragma unroll
            for (int fo = 0; fo < F; ++fo)
                acc[fo] += e * wr[fo];
        }
    }

    // combine 16 K-partials -> wave 0 (4 rounds, float4 LDS)
    for (int half = 8; half >= 1; half >>= 1) {
        if (w >= half && w < 2 * half) {
            float4* cb = (float4*)&comb[w - half][lane][0];
            #pragma unroll
            for (int j = 0; j < 9; ++j)
                cb[j] = make_float4(acc[4*j], acc[4*j+1], acc[4*j+2], acc[4*j+3]);
        }
        __syncthreads();
        if (w < half) {
            const float4* cb = (const float4*)&comb[w][lane][0];
            #pragma unroll
            for (int j = 0; j < 9; ++j) {
                float4 v = cb[j];
                acc[4*j]   += v.x; acc[4*j+1] += v.y;
                acc[4*j+2] += v.z; acc[4*j+3] += v.w;
            }
        }
        __syncthreads();
    }

    if (w == 0) {
        int t = t0 + lane;
        if (t < T1) {
            #pragma unroll
            for (int fo = 0; fo < F; ++fo) {
                float s2 = bnz[2 * F + fo], o2 = bnz[3 * F + fo];
                h2[(b * F + fo) * T1 + t] = elu_f(acc[fo] * s2 + o2);
            }
        }
    }
}

// ---- K2a: pool3 precompute -> P[bf][944] -----------------------------------
// P[s] = mean(h2[s..s+2]); computed once instead of 9x re-derivation in qconv.
// 2.2 MB, L2-resident for K2b. Indices >= valid range clamp (values only feed
// write-guarded lanes downstream).
__global__ __launch_bounds__(256) void k_pool(
    const float* __restrict__ h2, float* __restrict__ P)
{
    const int bf = blockIdx.x;
    const float* hr = h2 + (size_t)bf * T1;
    float* Pr = P + (size_t)bf * PSP;
    for (int i = threadIdx.x; i < PSP; i += 256) {
        int s0 = i     < T1 - 1 ? i     : T1 - 1;
        int s1 = i + 1 < T1 - 1 ? i + 1 : T1 - 1;
        int s2 = i + 2 < T1 - 1 ? i + 2 : T1 - 1;
        Pr[i] = (hr[s0] + hr[s1] + hr[s2]) * (1.f / 3.f);
    }
}

// ---- K2b: dilated conv + bn_c + elu -> A[bf][u]  (pipe-separated) ----------
// v2: NO LDS, NO barriers, NO split-K. Wave = one fo-triple (12 waves cover
// 36 fo); each wave does the FULL 36f x 15k reduction into acc[3]/thread.
//   * P   -> VMEM (vmcnt): per f, 15 independent dword loads, imm offsets.
//   * wcQ -> SMEM (lgkm, DS-free): 60 contiguous floats per f -> wide s_loads.
// The two streams wait on different counters -> no cross-serialization
// (rounds 2-6 qconv mixed ds_read with s_load -> lgkmcnt(0) drains, ~40 us).
// ~30 live VGPRs. grid (14, B) x 768.
__global__ __launch_bounds__(768) void k_qconv(
    const float* __restrict__ P, const float* __restrict__ wcQ,
    const float* __restrict__ bnz, float* __restrict__ A)
{
    const int tid  = threadIdx.x;
    const int lane = tid & 63;
    const int t3 = __builtin_amdgcn_readfirstlane(tid >> 6);  // 0..11
    const int b  = blockIdx.y;
    const int u0 = blockIdx.x * 64;
    const int fo0 = t3 * 3;

    const float* wq = wcQ + t3 * (36 * 60);

    float a0 = 0.f, a1 = 0.f, a2 = 0.f;

    for (int f = 0; f < F; ++f) {
        const float* Pr = P + (size_t)(b * F + f) * PSP + u0 + lane;
        const float* wf = wq + f * 60;            // wave-uniform, 60 consec
        #pragma unroll
        for (int k = 0; k < KS; ++k) {
            float pv = Pr[3 * k];                 // VMEM, imm offset 12*k
            a0 += pv * wf[4 * k + 0];
            a1 += pv * wf[4 * k + 1];
            a2 += pv * wf[4 * k + 2];
        }
    }

    int u = u0 + lane;
    if (u < UN) {
        float sc0 = bnz[4 * F + fo0 + 0], oc0 = bnz[5 * F + fo0 + 0];
        float sc1 = bnz[4 * F + fo0 + 1], oc1 = bnz[5 * F + fo0 + 1];
        float sc2 = bnz[4 * F + fo0 + 2], oc2 = bnz[5 * F + fo0 + 2];
        A[((size_t)(b * F + fo0 + 0)) * UN + u] = elu_f(a0 * sc0 + oc0);
        A[((size_t)(b * F + fo0 + 1)) * UN + u] = elu_f(a1 * sc1 + oc1);
        A[((size_t)(b * F + fo0 + 2)) * UN + u] = elu_f(a2 * sc2 + oc2);
    }
}

// ---- K3: window sums over finished A + fused FC -> atomicAdd out -----------
__global__ __launch_bounds__(256) void k_wins(
    const float* __restrict__ A, const float* __restrict__ w_fc,
    float* __restrict__ out)
{
    __shared__ float Es[UN];
    __shared__ float G[GN];
    __shared__ float Ws[WN];
    __shared__ float Sm[M43];
    const int tid = threadIdx.x;
    const int bf = blockIdx.x;
    const int b = bf / F, f = bf % F;
    for (int i = tid; i < UN; i += 256)
        Es[i] = A[(size_t)bf * UN + i];
    __syncthreads();
    for (int q = tid; q < GN; q += 256)
        G[q] = Es[3 * q] + Es[3 * q + 1] + Es[3 * q + 2];
    __syncthreads();
    if (tid < WN) {
        float a = 0.f;
        for (int q = tid; q < tid + 167; ++q) a += G[q];
        Ws[tid] = a;
    }
    __syncthreads();
    if (tid < M43)
        Sm[tid] = (Ws[3 * tid] + Ws[3 * tid + 1] + Ws[3 * tid + 2]) * (1.f / 3.f);
    __syncthreads();
    if (tid < 4) {
        const float* wr = w_fc + tid * FLAT + f * M43;
        float a = 0.f;
        #pragma unroll 43
        for (int m = 0; m < M43; ++m) a += Sm[m] * wr[m];
        atomicAdd(&out[b * 4 + tid], a * (1.f / 501.f));
    }
}

extern "C" void kernel_launch(void* const* d_in, const int* in_sizes, int n_in,
                              void* d_out, int out_size, void* d_ws, size_t ws_size,
                              hipStream_t stream) {
    const float* x    = (const float*)d_in[0];
    const float* w_t  = (const float*)d_in[1];
    const float* b_t  = (const float*)d_in[2];
    const float* g_t  = (const float*)d_in[3];
    const float* be_t = (const float*)d_in[4];
    const float* m_t  = (const float*)d_in[5];
    const float* v_t  = (const float*)d_in[6];
    const float* w_s  = (const float*)d_in[7];
    const float* b_s  = (const float*)d_in[8];
    const float* g_s  = (const float*)d_in[9];
    const float* be_s = (const float*)d_in[10];
    const float* m_s  = (const float*)d_in[11];
    const float* v_s  = (const float*)d_in[12];
    const float* w_c  = (const float*)d_in[13];
    const float* b_c  = (const float*)d_in[14];
    const float* g_c  = (const float*)d_in[15];
    const float* be_c = (const float*)d_in[16];
    const float* m_c  = (const float*)d_in[17];
    const float* v_c  = (const float*)d_in[18];
    const float* w_fc = (const float*)d_in[19];
    const float* b_fc = (const float*)d_in[20];

    float* ws   = (float*)d_ws;
    float* h2   = ws + H2_OFF;
    float* A    = ws + A_OFF;
    float* P    = ws + P_OFF;
    float* wtT  = ws + WTT_OFF;
    float* wsTp = ws + WST_OFF;
    float* wcQ  = ws + WCQ_OFF;
    float* bnz  = ws + BN_OFF;
    float* out  = (float*)d_out;

    k_prep<<<dim3(128), 256, 0, stream>>>(
        w_t, w_s, w_c, b_t, g_t, be_t, m_t, v_t,
        b_s, g_s, be_s, m_s, v_s, b_c, g_c, be_c, m_c, v_c, b_fc,
        wtT, wsTp, wcQ, bnz, out);

    k_fused<<<dim3(15, B), 1024, 0, stream>>>(x, wtT, wsTp, bnz, h2);
    k_pool<<<dim3(BF), 256, 0, stream>>>(h2, P);
    k_qconv<<<dim3(14, B), 768, 0, stream>>>(P, wcQ, bnz, A);
    k_wins<<<dim3(BF), 256, 0, stream>>>(A, w_fc, out);
}